// Round 1
// baseline (5336.480 us; speedup 1.0000x reference)
//
#include <hip/hip_runtime.h>
#include <cstdint>

#define T_STEPS 2048
#define HID 256
#define TSTRIDE 16384  // f16 per time-slot (4 bi-chunks x 4096)

typedef _Float16 half8 __attribute__((ext_vector_type(8)));
typedef float f32x4 __attribute__((ext_vector_type(4)));

// tanh(x) = 1 - 2/(exp2(2*log2e*x)+1): 4 VALU ops. Saturates at +-inf.
__device__ __forceinline__ float tanh_fast(float x){
  float e = __builtin_amdgcn_exp2f(x * 2.8853900817779268f);
  float r = __builtin_amdgcn_rcpf(e + 1.0f);
  return __builtin_fmaf(-2.0f, r, 1.0f);
}

// Load 8 consecutive fp32, round-convert to an MFMA f16x8 fragment.
__device__ __forceinline__ half8 cvt_frag8(const float* __restrict__ p){
  float4 a = *(const float4*)p;
  float4 b = *(const float4*)(p + 4);
  half8 h;
  h[0]=(_Float16)a.x; h[1]=(_Float16)a.y; h[2]=(_Float16)a.z; h[3]=(_Float16)a.w;
  h[4]=(_Float16)b.x; h[5]=(_Float16)b.y; h[6]=(_Float16)b.z; h[7]=(_Float16)b.w;
  return h;
}

// ---------------------------------------------------------------------------
// gemm_xp0: xp0[t,b,h] = x[t,b,:]·W_ih0[h,:] + b_ih0[h] + b_hh0[h], f16.
// chunk(t,bi) = xp + (t*4 + bi)*4096 f16; within chunk, 16B frag c = kc*64+l
// holds h1-layout data: element of frag (kc,l): batch lm=l&15,
// k = kc*32 + (l>>4)*8 + e. (Same layout the fused kernels consume.)
// ---------------------------------------------------------------------------
__global__ __launch_bounds__(512, 2) void gemm_xp0(
    const float* __restrict__ x, const float* __restrict__ W,
    const float* __restrict__ b1, const float* __restrict__ b2,
    _Float16* __restrict__ xp)
{
  const int t = blockIdx.x, tid = threadIdx.x;
  const int gw = tid >> 6, l = tid & 63;
  const int ng = gw & 1, mg = gw >> 1;
  const int lm = l & 15, lq = l >> 4;

  half8 Af[4][8];
  #pragma unroll
  for (int mt4 = 0; mt4 < 4; ++mt4)
    #pragma unroll
    for (int kc = 0; kc < 8; ++kc)
      Af[mt4][kc] = cvt_frag8(W + (long)(mg*64 + mt4*16 + lm)*HID + kc*32 + lq*8);

  half8 Bf[2][8];
  #pragma unroll
  for (int nt = 0; nt < 2; ++nt)
    #pragma unroll
    for (int kc = 0; kc < 8; ++kc)
      Bf[nt][kc] = cvt_frag8(x + ((long)t*64 + ng*32 + nt*16 + lm)*HID + kc*32 + lq*8);

  f32x4 acc[4][2];
  #pragma unroll
  for (int mt4 = 0; mt4 < 4; ++mt4)
    #pragma unroll
    for (int nt = 0; nt < 2; ++nt)
      acc[mt4][nt] = (f32x4){0.f,0.f,0.f,0.f};

  #pragma unroll
  for (int kc = 0; kc < 8; ++kc)
    #pragma unroll
    for (int mt4 = 0; mt4 < 4; ++mt4)
      #pragma unroll
      for (int nt = 0; nt < 2; ++nt)
        acc[mt4][nt] = __builtin_amdgcn_mfma_f32_16x16x32_f16(
            Af[mt4][kc], Bf[nt][kc], acc[mt4][nt], 0, 0, 0);

  _Float16* chunk0 = xp + ((long)t*4 + ng*2)*4096;
  #pragma unroll
  for (int wp = 0; wp < 2; ++wp){
    const int h0a = mg*64 + (2*wp    )*16 + lq*4;
    const int h0b = mg*64 + (2*wp + 1)*16 + lq*4;
    float4 ba1 = *(const float4*)(b1 + h0a), ba2 = *(const float4*)(b2 + h0a);
    float4 bb1 = *(const float4*)(b1 + h0b), bb2 = *(const float4*)(b2 + h0b);
    #pragma unroll
    for (int nt = 0; nt < 2; ++nt){
      f32x4 v0 = acc[2*wp][nt], v1 = acc[2*wp+1][nt];
      union { _Float16 h[8]; uint4 u; } pk;
      pk.h[0]=(_Float16)(v0[0]+ba1.x+ba2.x); pk.h[1]=(_Float16)(v0[1]+ba1.y+ba2.y);
      pk.h[2]=(_Float16)(v0[2]+ba1.z+ba2.z); pk.h[3]=(_Float16)(v0[3]+ba1.w+ba2.w);
      pk.h[4]=(_Float16)(v1[0]+bb1.x+bb2.x); pk.h[5]=(_Float16)(v1[1]+bb1.y+bb2.y);
      pk.h[6]=(_Float16)(v1[2]+bb1.z+bb2.z); pk.h[7]=(_Float16)(v1[3]+bb1.w+bb2.w);
      *(uint4*)(chunk0 + nt*4096 + ((mg*2 + wp)*64 + l)*8) = pk.u;
    }
  }
}

// ---------------------------------------------------------------------------
// fused_pipe: grid = 8. Blocks 0-3 = layer-1 producers (one per 16-batch
// group); blocks 4-7 = layer-2 consumers. Producer streams h1(t) into the
// dead xp0 slot of step t (in place, agent/sc1 stores by 4 dedicated store
// waves) and publishes a release flag; producer lead grows (its step is
// ~2x cheaper), so consumer polls are free in steady state.
// Consumer = old GEMM1+GEMM2, but GEMM1's B (h1) comes from GLOBAL register
// prefetch -> consumer LDS traffic drops from 192 to 64 b128 reads/step and
// only ONE barrier/step remains. Correct under any XCD placement (agent
// scope); 8 blocks are always co-resident, so the spin cannot deadlock.
// ---------------------------------------------------------------------------
__global__ __launch_bounds__(512, 2) void fused_pipe(
    _Float16* __restrict__ xp,                 // xp0 in; overwritten in place by h1
    const float* __restrict__ Whh0, const float* __restrict__ Wih1,
    const float* __restrict__ Whh1,
    const float* __restrict__ b1, const float* __restrict__ b2,
    unsigned long long* __restrict__ flags,    // one per producer, 128B apart
    _Float16* __restrict__ hout)
{
  __shared__ __align__(16) _Float16 hsb[2][16][264];   // h1 (prod) / h2 (cons) state
  const int tid = threadIdx.x;
  const int w = tid >> 6, l = tid & 63;
  const int lm = l & 15, lq = l >> 4;

  // zero initial state (t=0 reads buffer index 1)
  for (int i = tid; i < 16*264; i += 512) (&hsb[1][0][0])[i] = (_Float16)0.f;

  if (blockIdx.x < 4) {
    // ======================= PRODUCER (layer 1) =======================
    const int bi = blockIdx.x;
    unsigned long long* flag = flags + (size_t)bi*16;
    _Float16* chunk0 = xp + (size_t)bi*4096;

    if (w < 4) {
      // ---- compute waves: rows w*64 .. w*64+63 (mt = 0..3) ----
      half8 A0[4][8];
      #pragma unroll
      for (int mt = 0; mt < 4; ++mt)
        #pragma unroll
        for (int kc = 0; kc < 8; ++kc)
          A0[mt][kc] = cvt_frag8(Whh0 + (size_t)(w*64 + mt*16 + lm)*HID + kc*32 + lq*8);
      __syncthreads();

      // xp fragments for t=0: chunks of old waves 2w (mt0,1) and 2w+1 (mt2,3)
      uint4 xva = *(const uint4*)(chunk0 + ((2*w    )*64 + l)*8);
      uint4 xvb = *(const uint4*)(chunk0 + ((2*w + 1)*64 + l)*8);

      for (int t = 0; t <= T_STEPS; ++t){
        const int pb = (t + 1) & 1, cb = t & 1;
        if (t < T_STEPS){
          union { uint4 u; _Float16 h[8]; } xa, xb;
          xa.u = xva; xb.u = xvb;
          f32x4 acc[4];
          acc[0][0]=(float)xa.h[0]; acc[0][1]=(float)xa.h[1]; acc[0][2]=(float)xa.h[2]; acc[0][3]=(float)xa.h[3];
          acc[1][0]=(float)xa.h[4]; acc[1][1]=(float)xa.h[5]; acc[1][2]=(float)xa.h[6]; acc[1][3]=(float)xa.h[7];
          acc[2][0]=(float)xb.h[0]; acc[2][1]=(float)xb.h[1]; acc[2][2]=(float)xb.h[2]; acc[2][3]=(float)xb.h[3];
          acc[3][0]=(float)xb.h[4]; acc[3][1]=(float)xb.h[5]; acc[3][2]=(float)xb.h[6]; acc[3][3]=(float)xb.h[7];

          if (t + 1 < T_STEPS){   // prefetch next xp slot (read before it is overwritten)
            const _Float16* nx = chunk0 + (size_t)(t+1)*TSTRIDE;
            xva = *(const uint4*)(nx + ((2*w    )*64 + l)*8);
            xvb = *(const uint4*)(nx + ((2*w + 1)*64 + l)*8);
          }

          #pragma unroll
          for (int kc = 0; kc < 8; ++kc){
            half8 B = *(const half8*)&hsb[pb][lm][kc*32 + lq*8];
            acc[0] = __builtin_amdgcn_mfma_f32_16x16x32_f16(A0[0][kc], B, acc[0], 0,0,0);
            acc[1] = __builtin_amdgcn_mfma_f32_16x16x32_f16(A0[1][kc], B, acc[1], 0,0,0);
            acc[2] = __builtin_amdgcn_mfma_f32_16x16x32_f16(A0[2][kc], B, acc[2], 0,0,0);
            acc[3] = __builtin_amdgcn_mfma_f32_16x16x32_f16(A0[3][kc], B, acc[3], 0,0,0);
          }

          #pragma unroll
          for (int mt = 0; mt < 4; ++mt){
            union { _Float16 h[4]; unsigned long long u; } p;
            p.h[0]=(_Float16)tanh_fast(acc[mt][0]); p.h[1]=(_Float16)tanh_fast(acc[mt][1]);
            p.h[2]=(_Float16)tanh_fast(acc[mt][2]); p.h[3]=(_Float16)tanh_fast(acc[mt][3]);
            *(unsigned long long*)&hsb[cb][lm][w*64 + mt*16 + lq*4] = p.u;
          }
        }
        __syncthreads();
      }
    } else {
      // ---- store waves: publish h1(t-1) (from LDS pb) to slot(t-1), sc1 ----
      __syncthreads();   // match compute pre-loop barrier
      const int kcA = w - 4;            // this wave handles frags kcA and kcA+4
      for (int t = 0; t <= T_STEPS; ++t){
        const int pb = (t + 1) & 1;
        if (t > 0){
          union { half8 h; unsigned long long q[2]; } fa, fb;
          fa.h = *(const half8*)&hsb[pb][lm][kcA*32 + lq*8];
          fb.h = *(const half8*)&hsb[pb][lm][(kcA+4)*32 + lq*8];
          _Float16* slot = chunk0 + (size_t)(t-1)*TSTRIDE;
          unsigned long long* dA = (unsigned long long*)(slot + ((size_t)kcA*64 + l)*8);
          unsigned long long* dB = (unsigned long long*)(slot + ((size_t)(kcA+4)*64 + l)*8);
          __hip_atomic_store(dA,   fa.q[0], __ATOMIC_RELAXED, __HIP_MEMORY_SCOPE_AGENT);
          __hip_atomic_store(dA+1, fa.q[1], __ATOMIC_RELAXED, __HIP_MEMORY_SCOPE_AGENT);
          __hip_atomic_store(dB,   fb.q[0], __ATOMIC_RELAXED, __HIP_MEMORY_SCOPE_AGENT);
          __hip_atomic_store(dB+1, fb.q[1], __ATOMIC_RELAXED, __HIP_MEMORY_SCOPE_AGENT);
        }
        __syncthreads();  // barrier drains vmcnt -> all 4 waves' stores visible
        if (tid == 256 && t > 0)
          __hip_atomic_store(flag, (unsigned long long)t,
                             __ATOMIC_RELEASE, __HIP_MEMORY_SCOPE_AGENT);
      }
    }
  } else {
    // ======================= CONSUMER (layer 2) =======================
    const int bi = blockIdx.x - 4;
    const unsigned long long* flag = flags + (size_t)bi*16;
    const _Float16* chunk0 = xp + (size_t)bi*4096;

    half8 A1[2][8], A2[2][8];
    #pragma unroll
    for (int mt = 0; mt < 2; ++mt)
      #pragma unroll
      for (int kc = 0; kc < 8; ++kc){
        const size_t r = (size_t)(w*32 + mt*16 + lm)*HID + kc*32 + lq*8;
        A1[mt][kc] = cvt_frag8(Wih1 + r);
        A2[mt][kc] = cvt_frag8(Whh1 + r);
      }
    f32x4 biasf[2];
    #pragma unroll
    for (int mt = 0; mt < 2; ++mt){
      const int h0 = w*32 + mt*16 + lq*4;
      f32x4 b;
      b[0]=b1[h0+0]+b2[h0+0]; b[1]=b1[h0+1]+b2[h0+1];
      b[2]=b1[h0+2]+b2[h0+2]; b[3]=b1[h0+3]+b2[h0+3];
      biasf[mt] = b;
    }
    __syncthreads();
    _Float16* hob = hout + ((size_t)bi*16 + lm)*HID + w*32 + lq*4;

    // wait for h1(0), load its fragments (acquire poll orders the data loads)
    while (__hip_atomic_load(flag, __ATOMIC_ACQUIRE, __HIP_MEMORY_SCOPE_AGENT) < 1ull)
      __builtin_amdgcn_s_sleep(2);
    half8 pfc[8], pfn[8];
    #pragma unroll
    for (int kc = 0; kc < 8; ++kc){
      const unsigned long long* s = (const unsigned long long*)(chunk0 + ((size_t)kc*64 + l)*8);
      union { half8 h; unsigned long long q[2]; } u;
      u.q[0] = __hip_atomic_load(s,   __ATOMIC_RELAXED, __HIP_MEMORY_SCOPE_AGENT);
      u.q[1] = __hip_atomic_load(s+1, __ATOMIC_RELAXED, __HIP_MEMORY_SCOPE_AGENT);
      pfc[kc] = u.h;
    }

    for (int t = 0; t < T_STEPS; ++t){
      const int pb = (t + 1) & 1, cb = t & 1;
      f32x4 a0 = biasf[0], a1 = biasf[1];

      // GEMM1: bias + Wih1 · h1(t)  (B from registers — zero LDS)
      #pragma unroll
      for (int kc = 0; kc < 8; ++kc){
        a0 = __builtin_amdgcn_mfma_f32_16x16x32_f16(A1[0][kc], pfc[kc], a0, 0,0,0);
        a1 = __builtin_amdgcn_mfma_f32_16x16x32_f16(A1[1][kc], pfc[kc], a1, 0,0,0);
      }

      // prefetch h1(t+1); latency hidden under GEMM2 + tanh + barrier
      if (t + 1 < T_STEPS){
        while (__hip_atomic_load(flag, __ATOMIC_ACQUIRE, __HIP_MEMORY_SCOPE_AGENT)
               < (unsigned long long)(t + 2))
          __builtin_amdgcn_s_sleep(2);
        const _Float16* slot = chunk0 + (size_t)(t+1)*TSTRIDE;
        #pragma unroll
        for (int kc = 0; kc < 8; ++kc){
          const unsigned long long* s = (const unsigned long long*)(slot + ((size_t)kc*64 + l)*8);
          union { half8 h; unsigned long long q[2]; } u;
          u.q[0] = __hip_atomic_load(s,   __ATOMIC_RELAXED, __HIP_MEMORY_SCOPE_AGENT);
          u.q[1] = __hip_atomic_load(s+1, __ATOMIC_RELAXED, __HIP_MEMORY_SCOPE_AGENT);
          pfn[kc] = u.h;
        }
      }

      // GEMM2: += Whh1 · h2(t-1)  (B from LDS)
      #pragma unroll
      for (int kc = 0; kc < 8; ++kc){
        half8 B = *(const half8*)&hsb[pb][lm][kc*32 + lq*8];
        a0 = __builtin_amdgcn_mfma_f32_16x16x32_f16(A2[0][kc], B, a0, 0,0,0);
        a1 = __builtin_amdgcn_mfma_f32_16x16x32_f16(A2[1][kc], B, a1, 0,0,0);
      }

      // h2 = tanh(.) -> LDS state + global out (f16)
      union { _Float16 h[4]; unsigned long long u; } q0, q1;
      q0.h[0]=(_Float16)tanh_fast(a0[0]); q0.h[1]=(_Float16)tanh_fast(a0[1]);
      q0.h[2]=(_Float16)tanh_fast(a0[2]); q0.h[3]=(_Float16)tanh_fast(a0[3]);
      q1.h[0]=(_Float16)tanh_fast(a1[0]); q1.h[1]=(_Float16)tanh_fast(a1[1]);
      q1.h[2]=(_Float16)tanh_fast(a1[2]); q1.h[3]=(_Float16)tanh_fast(a1[3]);
      *(unsigned long long*)&hsb[cb][lm][w*32      + lq*4] = q0.u;
      *(unsigned long long*)&hsb[cb][lm][w*32 + 16 + lq*4] = q1.u;
      _Float16* o = hob + (size_t)t*64*HID;
      *(unsigned long long*)o        = q0.u;
      *(unsigned long long*)(o + 16) = q1.u;
      __syncthreads();

      if (t + 1 < T_STEPS){
        #pragma unroll
        for (int kc = 0; kc < 8; ++kc) pfc[kc] = pfn[kc];
      }
    }
  }
}

// f16 -> fp32 final output, full-device, HBM-bound (~192 MiB moved).
__global__ __launch_bounds__(256) void cvt_out(
    const _Float16* __restrict__ hin, float* __restrict__ out)
{
  const long i = ((long)blockIdx.x*256 + threadIdx.x)*8;
  half8 v = *(const half8*)(hin + i);
  float4 a, b;
  a.x=(float)v[0]; a.y=(float)v[1]; a.z=(float)v[2]; a.w=(float)v[3];
  b.x=(float)v[4]; b.y=(float)v[5]; b.z=(float)v[6]; b.w=(float)v[7];
  *(float4*)(out + i)     = a;
  *(float4*)(out + i + 4) = b;
}

// ---------------------------------------------------------------------------
// Buffers: d_out low 64 MiB = xp0 (f16), overwritten in place by h1 during
// fused_pipe (slot t is dead once the producer consumed it); flags (512 B)
// live at d_out + 64 MiB (dead region until cvt_out overwrites it at the
// end; re-zeroed in-stream every launch -> graph-replay safe).
// h2 f16 (64 MiB) -> d_ws; final fp32 -> d_out (128 MiB).
// ---------------------------------------------------------------------------
extern "C" void kernel_launch(void* const* d_in, const int* in_sizes, int n_in,
                              void* d_out, int out_size, void* d_ws, size_t ws_size,
                              hipStream_t stream)
{
  const float* x     = (const float*)d_in[0];
  const float* W_ih0 = (const float*)d_in[1];
  const float* W_hh0 = (const float*)d_in[2];
  const float* b_ih0 = (const float*)d_in[3];
  const float* b_hh0 = (const float*)d_in[4];
  const float* W_ih1 = (const float*)d_in[5];
  const float* W_hh1 = (const float*)d_in[6];
  const float* b_ih1 = (const float*)d_in[7];
  const float* b_hh1 = (const float*)d_in[8];

  _Float16* xp0 = (_Float16*)d_out;
  unsigned long long* flags =
      (unsigned long long*)((char*)d_out + (size_t)T_STEPS*64*HID*2);
  _Float16* h2  = (_Float16*)d_ws;

  gemm_xp0<<<T_STEPS, 512, 0, stream>>>(x, W_ih0, b_ih0, b_hh0, xp0);
  hipMemsetAsync(flags, 0, 1024, stream);
  fused_pipe<<<8, 512, 0, stream>>>(xp0, W_hh0, W_ih1, W_hh1, b_ih1, b_hh1,
                                    flags, h2);
  cvt_out<<<(T_STEPS*64*HID)/(256*8), 256, 0, stream>>>(h2, (float*)d_out);
}

// Round 2
// 5088.900 us; speedup vs baseline: 1.0487x; 1.0487x over previous
//
#include <hip/hip_runtime.h>
#include <cstdint>

#define T_STEPS 2048
#define HID 256
#define TSTRIDE 16384  // f16 per time-slot (4 bi-chunks x 4096)

typedef _Float16 half8 __attribute__((ext_vector_type(8)));
typedef float f32x4 __attribute__((ext_vector_type(4)));

// tanh(x) = 1 - 2/(exp2(2*log2e*x)+1): 4 VALU ops. Saturates at +-inf.
__device__ __forceinline__ float tanh_fast(float x){
  float e = __builtin_amdgcn_exp2f(x * 2.8853900817779268f);
  float r = __builtin_amdgcn_rcpf(e + 1.0f);
  return __builtin_fmaf(-2.0f, r, 1.0f);
}

// Load 8 consecutive fp32, round-convert to an MFMA f16x8 fragment.
__device__ __forceinline__ half8 cvt_frag8(const float* __restrict__ p){
  float4 a = *(const float4*)p;
  float4 b = *(const float4*)(p + 4);
  half8 h;
  h[0]=(_Float16)a.x; h[1]=(_Float16)a.y; h[2]=(_Float16)a.z; h[3]=(_Float16)a.w;
  h[4]=(_Float16)b.x; h[5]=(_Float16)b.y; h[6]=(_Float16)b.z; h[7]=(_Float16)b.w;
  return h;
}

// ---------------------------------------------------------------------------
// gemm_xp0: xp0[t,b,h] = x[t,b,:]·W_ih0[h,:] + b_ih0[h] + b_hh0[h], f16.
// chunk(t,bi) = xp + (t*4 + bi)*4096 f16. Frag f = w'*64 + l (w' = 0..7)
// holds acc-layout data: element mt*4+r -> hidden w'*32+mt*16+lq*4+r,
// batch lm  (lm = l&15, lq = l>>4). One dwordx4 per (wp,nt) store.
// ---------------------------------------------------------------------------
__global__ __launch_bounds__(512, 2) void gemm_xp0(
    const float* __restrict__ x, const float* __restrict__ W,
    const float* __restrict__ b1, const float* __restrict__ b2,
    _Float16* __restrict__ xp)
{
  const int t = blockIdx.x, tid = threadIdx.x;
  const int gw = tid >> 6, l = tid & 63;
  const int ng = gw & 1, mg = gw >> 1;
  const int lm = l & 15, lq = l >> 4;

  half8 Af[4][8];
  #pragma unroll
  for (int mt4 = 0; mt4 < 4; ++mt4)
    #pragma unroll
    for (int kc = 0; kc < 8; ++kc)
      Af[mt4][kc] = cvt_frag8(W + (long)(mg*64 + mt4*16 + lm)*HID + kc*32 + lq*8);

  half8 Bf[2][8];
  #pragma unroll
  for (int nt = 0; nt < 2; ++nt)
    #pragma unroll
    for (int kc = 0; kc < 8; ++kc)
      Bf[nt][kc] = cvt_frag8(x + ((long)t*64 + ng*32 + nt*16 + lm)*HID + kc*32 + lq*8);

  f32x4 acc[4][2];
  #pragma unroll
  for (int mt4 = 0; mt4 < 4; ++mt4)
    #pragma unroll
    for (int nt = 0; nt < 2; ++nt)
      acc[mt4][nt] = (f32x4){0.f,0.f,0.f,0.f};

  #pragma unroll
  for (int kc = 0; kc < 8; ++kc)
    #pragma unroll
    for (int mt4 = 0; mt4 < 4; ++mt4)
      #pragma unroll
      for (int nt = 0; nt < 2; ++nt)
        acc[mt4][nt] = __builtin_amdgcn_mfma_f32_16x16x32_f16(
            Af[mt4][kc], Bf[nt][kc], acc[mt4][nt], 0, 0, 0);

  _Float16* chunk0 = xp + ((long)t*4 + ng*2)*4096;
  #pragma unroll
  for (int wp = 0; wp < 2; ++wp){
    const int h0a = mg*64 + (2*wp    )*16 + lq*4;
    const int h0b = mg*64 + (2*wp + 1)*16 + lq*4;
    float4 ba1 = *(const float4*)(b1 + h0a), ba2 = *(const float4*)(b2 + h0a);
    float4 bb1 = *(const float4*)(b1 + h0b), bb2 = *(const float4*)(b2 + h0b);
    #pragma unroll
    for (int nt = 0; nt < 2; ++nt){
      f32x4 v0 = acc[2*wp][nt], v1 = acc[2*wp+1][nt];
      union { _Float16 h[8]; uint4 u; } pk;
      pk.h[0]=(_Float16)(v0[0]+ba1.x+ba2.x); pk.h[1]=(_Float16)(v0[1]+ba1.y+ba2.y);
      pk.h[2]=(_Float16)(v0[2]+ba1.z+ba2.z); pk.h[3]=(_Float16)(v0[3]+ba1.w+ba2.w);
      pk.h[4]=(_Float16)(v1[0]+bb1.x+bb2.x); pk.h[5]=(_Float16)(v1[1]+bb1.y+bb2.y);
      pk.h[6]=(_Float16)(v1[2]+bb1.z+bb2.z); pk.h[7]=(_Float16)(v1[3]+bb1.w+bb2.w);
      *(uint4*)(chunk0 + nt*4096 + ((mg*2 + wp)*64 + l)*8) = pk.u;
    }
  }
}

// ---------------------------------------------------------------------------
// fused_rec: both layers, one block per 16-batch group (grid = 4).
// 4 waves x 64 hidden rows each (mt = 0..3) -> LDS B-fragment traffic HALVES
// vs the 8-wave version (B-frags are identical across waves; traffic scales
// with wave count): 96 ds_read_b128/step instead of 192.
// h1/h2 states live in LDS in FRAGMENT-LINEAR layout [kc][lane][8]: the
// B-read address is (kc*64+l)*16 -> consecutive lanes hit consecutive 16B ->
// zero bank conflicts (vs 4-way with the old [16][264] layout, 7.3M cycles).
// Phase 1 runs GEMM0 (h1 recurrence) and GEMM2 (h2 recurrence, operand ready
// at step start) concurrently: two independent MFMA chains for ILP.
// Per wave per step: 24 ds_read_b128, 96 MFMA, 2 barriers.
// __launch_bounds__(256,1): 1 wave/SIMD -> 512-reg unified budget for the
// 3 x 128 A-fragment registers (compiler places them in AGPRs).
// ---------------------------------------------------------------------------
__global__ __launch_bounds__(256, 1) void fused_rec(
    const _Float16* __restrict__ xp,
    const float* __restrict__ Whh0, const float* __restrict__ Wih1,
    const float* __restrict__ Whh1,
    const float* __restrict__ b1, const float* __restrict__ b2,
    _Float16* __restrict__ hout)
{
  // [buf][kc][lane][elem] fragment-linear f16 states, double-buffered.
  __shared__ __align__(16) _Float16 h1f[2][8][64][8];
  __shared__ __align__(16) _Float16 h2f[2][8][64][8];
  const int bi = blockIdx.x, tid = threadIdx.x;
  const int w = tid >> 6, l = tid & 63;
  const int lm = l & 15, lq = l >> 4;

  // zero initial states (t=0 reads buffer index 1)
  for (int i = tid; i < 8*64*8; i += 256){
    (&h1f[1][0][0][0])[i] = (_Float16)0.f;
    (&h2f[1][0][0][0])[i] = (_Float16)0.f;
  }

  // register-resident A-fragments: rows w*64 + mt*16 + lm, mt = 0..3
  half8 A0[4][8], A1[4][8], A2[4][8];
  #pragma unroll
  for (int mt = 0; mt < 4; ++mt)
    #pragma unroll
    for (int kc = 0; kc < 8; ++kc){
      const size_t r = (size_t)(w*64 + mt*16 + lm)*HID + kc*32 + lq*8;
      A0[mt][kc] = cvt_frag8(Whh0 + r);
      A1[mt][kc] = cvt_frag8(Wih1 + r);
      A2[mt][kc] = cvt_frag8(Whh1 + r);
    }

  // layer-2 bias fragments (C-init of phase-1 GEMM2)
  f32x4 biasf[4];
  #pragma unroll
  for (int mt = 0; mt < 4; ++mt){
    const int h0 = w*64 + mt*16 + lq*4;
    f32x4 b;
    b[0]=b1[h0+0]+b2[h0+0]; b[1]=b1[h0+1]+b2[h0+1];
    b[2]=b1[h0+2]+b2[h0+2]; b[3]=b1[h0+3]+b2[h0+3];
    biasf[mt] = b;
  }
  __syncthreads();

  // xp fragments for t=0: acc-layout frags 2w (mt 0,1) and 2w+1 (mt 2,3)
  const _Float16* chunk0 = xp + (size_t)bi*4096;
  uint4 xva = *(const uint4*)(chunk0 + ((2*w    )*64 + l)*8);
  uint4 xvb = *(const uint4*)(chunk0 + ((2*w + 1)*64 + l)*8);

  _Float16* hob = hout + ((size_t)bi*16 + lm)*HID + w*64 + lq*4;

  for (int t = 0; t < T_STEPS; ++t){
    const int pb = (t + 1) & 1, cb = t & 1;

    // acc1 init from xp0 fragment (f16 -> f32); acc2 init from bias
    union { uint4 u; _Float16 h[8]; } xa, xb;
    xa.u = xva; xb.u = xvb;
    f32x4 acc1[4], acc2[4];
    acc1[0][0]=(float)xa.h[0]; acc1[0][1]=(float)xa.h[1]; acc1[0][2]=(float)xa.h[2]; acc1[0][3]=(float)xa.h[3];
    acc1[1][0]=(float)xa.h[4]; acc1[1][1]=(float)xa.h[5]; acc1[1][2]=(float)xa.h[6]; acc1[1][3]=(float)xa.h[7];
    acc1[2][0]=(float)xb.h[0]; acc1[2][1]=(float)xb.h[1]; acc1[2][2]=(float)xb.h[2]; acc1[2][3]=(float)xb.h[3];
    acc1[3][0]=(float)xb.h[4]; acc1[3][1]=(float)xb.h[5]; acc1[3][2]=(float)xb.h[6]; acc1[3][3]=(float)xb.h[7];
    #pragma unroll
    for (int mt = 0; mt < 4; ++mt) acc2[mt] = biasf[mt];

    // prefetch next step's xp (latency hidden under this step's compute)
    if (t + 1 < T_STEPS){
      const _Float16* nx = chunk0 + (size_t)(t+1)*TSTRIDE;
      xva = *(const uint4*)(nx + ((2*w    )*64 + l)*8);
      xvb = *(const uint4*)(nx + ((2*w + 1)*64 + l)*8);
    }

    // ---- phase 1: GEMM0 (+= Whh0·h1_{t-1}) and GEMM2 (+= Whh1·h2_{t-1}) ----
    #pragma unroll
    for (int kc = 0; kc < 8; ++kc){
      half8 B0 = *(const half8*)&h1f[pb][kc][l][0];
      half8 B2 = *(const half8*)&h2f[pb][kc][l][0];
      #pragma unroll
      for (int mt = 0; mt < 4; ++mt){
        acc1[mt] = __builtin_amdgcn_mfma_f32_16x16x32_f16(A0[mt][kc], B0, acc1[mt], 0,0,0);
        acc2[mt] = __builtin_amdgcn_mfma_f32_16x16x32_f16(A2[mt][kc], B2, acc2[mt], 0,0,0);
      }
    }

    // h1 = tanh(.) -> LDS in B-fragment layout.
    // Thread value (row k = w*64+mt*16+lq*4+r, batch lm) belongs to frag
    // kc' = 2w + (mt>>1), lane l' = lm + 16*((mt&1)*2 + (lq>>1)), elem (lq&1)*4+r.
    #pragma unroll
    for (int mt = 0; mt < 4; ++mt){
      union { _Float16 h[4]; unsigned long long u; } p;
      p.h[0]=(_Float16)tanh_fast(acc1[mt][0]); p.h[1]=(_Float16)tanh_fast(acc1[mt][1]);
      p.h[2]=(_Float16)tanh_fast(acc1[mt][2]); p.h[3]=(_Float16)tanh_fast(acc1[mt][3]);
      const int kcd = 2*w + (mt>>1);
      const int lp  = lm + 16*((mt&1)*2 + (lq>>1));
      *(unsigned long long*)&h1f[cb][kcd][lp][(lq&1)*4] = p.u;
    }
    __syncthreads();  // h1_t visible to all waves

    // ---- phase 2: GEMM1 (+= Wih1·h1_t) ----
    #pragma unroll
    for (int kc = 0; kc < 8; ++kc){
      half8 B1 = *(const half8*)&h1f[cb][kc][l][0];
      #pragma unroll
      for (int mt = 0; mt < 4; ++mt)
        acc2[mt] = __builtin_amdgcn_mfma_f32_16x16x32_f16(A1[mt][kc], B1, acc2[mt], 0,0,0);
    }

    // h2 = tanh(.) -> LDS state (B-frag layout) + global out (C layout, f16)
    #pragma unroll
    for (int mt = 0; mt < 4; ++mt){
      union { _Float16 h[4]; unsigned long long u; } q;
      q.h[0]=(_Float16)tanh_fast(acc2[mt][0]); q.h[1]=(_Float16)tanh_fast(acc2[mt][1]);
      q.h[2]=(_Float16)tanh_fast(acc2[mt][2]); q.h[3]=(_Float16)tanh_fast(acc2[mt][3]);
      const int kcd = 2*w + (mt>>1);
      const int lp  = lm + 16*((mt&1)*2 + (lq>>1));
      *(unsigned long long*)&h2f[cb][kcd][lp][(lq&1)*4] = q.u;
      *(unsigned long long*)(hob + (size_t)t*64*HID + mt*16) = q.u;
    }
    __syncthreads();  // h2_t + buffer rotation safety
  }
}

// f16 -> fp32 final output, full-device, HBM-bound (~192 MiB moved).
__global__ __launch_bounds__(256) void cvt_out(
    const _Float16* __restrict__ hin, float* __restrict__ out)
{
  const long i = ((long)blockIdx.x*256 + threadIdx.x)*8;
  half8 v = *(const half8*)(hin + i);
  float4 a, b;
  a.x=(float)v[0]; a.y=(float)v[1]; a.z=(float)v[2]; a.w=(float)v[3];
  b.x=(float)v[4]; b.y=(float)v[5]; b.z=(float)v[6]; b.w=(float)v[7];
  *(float4*)(out + i)     = a;
  *(float4*)(out + i + 4) = b;
}

// ---------------------------------------------------------------------------
// Buffers: xp0 f16 (64 MiB) -> d_out low half (dead before cvt_out runs);
// h2 f16 (64 MiB) -> d_ws; final fp32 -> d_out.
// ---------------------------------------------------------------------------
extern "C" void kernel_launch(void* const* d_in, const int* in_sizes, int n_in,
                              void* d_out, int out_size, void* d_ws, size_t ws_size,
                              hipStream_t stream)
{
  const float* x     = (const float*)d_in[0];
  const float* W_ih0 = (const float*)d_in[1];
  const float* W_hh0 = (const float*)d_in[2];
  const float* b_ih0 = (const float*)d_in[3];
  const float* b_hh0 = (const float*)d_in[4];
  const float* W_ih1 = (const float*)d_in[5];
  const float* W_hh1 = (const float*)d_in[6];
  const float* b_ih1 = (const float*)d_in[7];
  const float* b_hh1 = (const float*)d_in[8];

  _Float16* xp0 = (_Float16*)d_out;
  _Float16* h2  = (_Float16*)d_ws;

  gemm_xp0<<<T_STEPS, 512, 0, stream>>>(x, W_ih0, b_ih0, b_hh0, xp0);
  fused_rec<<<4, 256, 0, stream>>>(xp0, W_hh0, W_ih1, W_hh1, b_ih1, b_hh1, h2);
  cvt_out<<<(T_STEPS*64*HID)/(256*8), 256, 0, stream>>>(h2, (float*)d_out);
}

// Round 3
// 2958.016 us; speedup vs baseline: 1.8041x; 1.7204x over previous
//
#include <hip/hip_runtime.h>
#include <cstdint>

#define T_STEPS 2048
#define HID 256
#define TSTRIDE 16384  // f16 per time-slot (4 bi-chunks x 4096)

typedef _Float16 half8 __attribute__((ext_vector_type(8)));
typedef float f32x4 __attribute__((ext_vector_type(4)));

// tanh(x) = 1 - 2/(exp2(2*log2e*x)+1): 4 VALU ops. Saturates at +-inf.
__device__ __forceinline__ float tanh_fast(float x){
  float e = __builtin_amdgcn_exp2f(x * 2.8853900817779268f);
  float r = __builtin_amdgcn_rcpf(e + 1.0f);
  return __builtin_fmaf(-2.0f, r, 1.0f);
}

// Load 8 consecutive fp32, round-convert to an MFMA f16x8 fragment.
__device__ __forceinline__ half8 cvt_frag8(const float* __restrict__ p){
  float4 a = *(const float4*)p;
  float4 b = *(const float4*)(p + 4);
  half8 h;
  h[0]=(_Float16)a.x; h[1]=(_Float16)a.y; h[2]=(_Float16)a.z; h[3]=(_Float16)a.w;
  h[4]=(_Float16)b.x; h[5]=(_Float16)b.y; h[6]=(_Float16)b.z; h[7]=(_Float16)b.w;
  return h;
}

// ---------------------------------------------------------------------------
// wcvt: pre-convert Whh0/Wih1/Whh1 to f16 MFMA A-fragments, laid out so the
// fused kernel's pre-loop load is 48 linear b128 loads per wave (no cvt, no
// address math in the recurrence). Frag (m, w, mt, kc) at f16 offset
// ((m*8+w)*16 + mt*8 + kc)*512 + l*8; lane l holds row w*32+mt*16+(l&15),
// k = kc*32 + (l>>4)*8 .. +7.  Total 384 KB.
// Round-0/2 post-mortem: with W left in f32, the compiler re-loaded and
// re-converted fragments from L2 EVERY STEP (192 regs never fit next to the
// working set) -> ~480 VALU/wave/step. This kernel kills that permanently.
// ---------------------------------------------------------------------------
__global__ __launch_bounds__(64) void wcvt(
    const float* __restrict__ W0, const float* __restrict__ W1,
    const float* __restrict__ W2, _Float16* __restrict__ wbuf)
{
  const int m = blockIdx.x >> 3, w = blockIdx.x & 7;
  const int l = threadIdx.x, lm = l & 15, lq = l >> 4;
  const float* W = (m == 0) ? W0 : (m == 1) ? W1 : W2;
  #pragma unroll
  for (int mt = 0; mt < 2; ++mt)
    #pragma unroll
    for (int kc = 0; kc < 8; ++kc){
      half8 f = cvt_frag8(W + (size_t)(w*32 + mt*16 + lm)*HID + kc*32 + lq*8);
      *(half8*)(wbuf + ((size_t)blockIdx.x*16 + mt*8 + kc)*512 + l*8) = f;
    }
}

// ---------------------------------------------------------------------------
// gemm_xp0: xp0[t,b,h] = x[t,b,:]·W_ih0[h,:] + b_ih0[h] + b_hh0[h], f16.
// chunk(t,bi) = xp + (t*4 + bi)*4096 f16. Frag f = w'*64 + l (w' = 0..7)
// holds acc-layout data: element mt*4+r -> hidden w'*32+mt*16+lq*4+r,
// batch lm  (lm = l&15, lq = l>>4). One dwordx4 per (wp,nt) store.
// ---------------------------------------------------------------------------
__global__ __launch_bounds__(512, 2) void gemm_xp0(
    const float* __restrict__ x, const float* __restrict__ W,
    const float* __restrict__ b1, const float* __restrict__ b2,
    _Float16* __restrict__ xp)
{
  const int t = blockIdx.x, tid = threadIdx.x;
  const int gw = tid >> 6, l = tid & 63;
  const int ng = gw & 1, mg = gw >> 1;
  const int lm = l & 15, lq = l >> 4;

  half8 Af[4][8];
  #pragma unroll
  for (int mt4 = 0; mt4 < 4; ++mt4)
    #pragma unroll
    for (int kc = 0; kc < 8; ++kc)
      Af[mt4][kc] = cvt_frag8(W + (long)(mg*64 + mt4*16 + lm)*HID + kc*32 + lq*8);

  half8 Bf[2][8];
  #pragma unroll
  for (int nt = 0; nt < 2; ++nt)
    #pragma unroll
    for (int kc = 0; kc < 8; ++kc)
      Bf[nt][kc] = cvt_frag8(x + ((long)t*64 + ng*32 + nt*16 + lm)*HID + kc*32 + lq*8);

  f32x4 acc[4][2];
  #pragma unroll
  for (int mt4 = 0; mt4 < 4; ++mt4)
    #pragma unroll
    for (int nt = 0; nt < 2; ++nt)
      acc[mt4][nt] = (f32x4){0.f,0.f,0.f,0.f};

  #pragma unroll
  for (int kc = 0; kc < 8; ++kc)
    #pragma unroll
    for (int mt4 = 0; mt4 < 4; ++mt4)
      #pragma unroll
      for (int nt = 0; nt < 2; ++nt)
        acc[mt4][nt] = __builtin_amdgcn_mfma_f32_16x16x32_f16(
            Af[mt4][kc], Bf[nt][kc], acc[mt4][nt], 0, 0, 0);

  _Float16* chunk0 = xp + ((long)t*4 + ng*2)*4096;
  #pragma unroll
  for (int wp = 0; wp < 2; ++wp){
    const int h0a = mg*64 + (2*wp    )*16 + lq*4;
    const int h0b = mg*64 + (2*wp + 1)*16 + lq*4;
    float4 ba1 = *(const float4*)(b1 + h0a), ba2 = *(const float4*)(b2 + h0a);
    float4 bb1 = *(const float4*)(b1 + h0b), bb2 = *(const float4*)(b2 + h0b);
    #pragma unroll
    for (int nt = 0; nt < 2; ++nt){
      f32x4 v0 = acc[2*wp][nt], v1 = acc[2*wp+1][nt];
      union { _Float16 h[8]; uint4 u; } pk;
      pk.h[0]=(_Float16)(v0[0]+ba1.x+ba2.x); pk.h[1]=(_Float16)(v0[1]+ba1.y+ba2.y);
      pk.h[2]=(_Float16)(v0[2]+ba1.z+ba2.z); pk.h[3]=(_Float16)(v0[3]+ba1.w+ba2.w);
      pk.h[4]=(_Float16)(v1[0]+bb1.x+bb2.x); pk.h[5]=(_Float16)(v1[1]+bb1.y+bb2.y);
      pk.h[6]=(_Float16)(v1[2]+bb1.z+bb2.z); pk.h[7]=(_Float16)(v1[3]+bb1.w+bb2.w);
      *(uint4*)(chunk0 + nt*4096 + ((mg*2 + wp)*64 + l)*8) = pk.u;
    }
  }
}

// ---------------------------------------------------------------------------
// fused_rec: both layers, one block per 16-batch group (grid = 4).
// SKEWED schedule: iteration t computes h1(t) = tanh(xp0(t) + Whh0·h1(t-1))
// AND h2(t-1) = tanh(bias + Wih1·h1(t-1) + Whh1·h2(t-2)) in ONE phase with
// ONE barrier. GEMM0 and GEMM1 share the SAME B operand h1(t-1): LDS reads
// drop to 16 b128/wave/step (128/block vs round-0's 192+conflicts).
// Double-buffer + single end-of-iter barrier is race-free: within an
// iteration reads hit [pb] and writes hit [cb] (disjoint); the barrier
// separates iterations.
// 8 waves x 32 rows, 2 waves/SIMD (launch_bounds(512,2) -> 256 regs/wave):
// A-frags = 192 regs (AGPR) + ~70 working VGPR. A-frags load as 48 linear
// b128 from wcvt's buffer (no per-step cvt -- the round-0 hidden cost).
// States in fragment-linear LDS [buf][kc][lane][8]: conflict-free b128 reads.
// ---------------------------------------------------------------------------
__global__ __launch_bounds__(512, 2) void fused_rec(
    const _Float16* __restrict__ xp, const _Float16* __restrict__ wbuf,
    const float* __restrict__ b1, const float* __restrict__ b2,
    _Float16* __restrict__ hout)
{
  __shared__ __align__(16) _Float16 h1f[2][8][64][8];
  __shared__ __align__(16) _Float16 h2f[2][8][64][8];
  const int bi = blockIdx.x, tid = threadIdx.x;
  const int w = tid >> 6, l = tid & 63;
  const int lm = l & 15, lq = l >> 4;

  // zero BOTH buffers (t=0 reads [1]; t=1 reads h2f[0] which must be 0)
  for (int i = tid; i < 2*8*64*8; i += 512){
    (&h1f[0][0][0][0])[i] = (_Float16)0.f;
    (&h2f[0][0][0][0])[i] = (_Float16)0.f;
  }

  // register-resident A-fragments from wcvt's layout: 48 linear b128 loads
  const _Float16* wb = wbuf + (size_t)w*16*512 + (size_t)l*8;
  half8 A0[2][8], A1[2][8], A2[2][8];
  #pragma unroll
  for (int mt = 0; mt < 2; ++mt)
    #pragma unroll
    for (int kc = 0; kc < 8; ++kc){
      A0[mt][kc] = *(const half8*)(wb +      0 + (mt*8 + kc)*512);
      A1[mt][kc] = *(const half8*)(wb +  65536 + (mt*8 + kc)*512);
      A2[mt][kc] = *(const half8*)(wb + 131072 + (mt*8 + kc)*512);
    }

  // layer-2 bias fragments (C-init of GEMM1)
  f32x4 biasf[2];
  #pragma unroll
  for (int mt = 0; mt < 2; ++mt){
    const int h0 = w*32 + mt*16 + lq*4;
    f32x4 b;
    b[0]=b1[h0+0]+b2[h0+0]; b[1]=b1[h0+1]+b2[h0+1];
    b[2]=b1[h0+2]+b2[h0+2]; b[3]=b1[h0+3]+b2[h0+3];
    biasf[mt] = b;
  }
  __syncthreads();

  const _Float16* chunk0 = xp + (size_t)bi*4096;
  uint4 xv = *(const uint4*)(chunk0 + ((size_t)w*64 + l)*8);   // xp0(0)
  _Float16* hob = hout + ((size_t)bi*16 + lm)*HID + w*32 + lq*4;

  for (int t = 0; t <= T_STEPS; ++t){
    const int pb = (t + 1) & 1, cb = t & 1;

    // acc1 init from xp0(t) fragment; acc2 init from bias
    union { uint4 u; _Float16 h[8]; } xa; xa.u = xv;
    f32x4 acc1[2], acc2[2];
    acc1[0][0]=(float)xa.h[0]; acc1[0][1]=(float)xa.h[1]; acc1[0][2]=(float)xa.h[2]; acc1[0][3]=(float)xa.h[3];
    acc1[1][0]=(float)xa.h[4]; acc1[1][1]=(float)xa.h[5]; acc1[1][2]=(float)xa.h[6]; acc1[1][3]=(float)xa.h[7];
    acc2[0] = biasf[0]; acc2[1] = biasf[1];

    // prefetch next step's xp (latency hidden under this step's compute)
    if (t + 1 < T_STEPS)
      xv = *(const uint4*)(chunk0 + (size_t)(t+1)*TSTRIDE + ((size_t)w*64 + l)*8);

    // one phase: GEMM0 (h1 rec) + GEMM1 (shares B1!) + GEMM2 (h2 rec)
    #pragma unroll
    for (int kc = 0; kc < 8; ++kc){
      half8 B1 = *(const half8*)&h1f[pb][kc][l][0];   // h1(t-1)
      half8 B2 = *(const half8*)&h2f[pb][kc][l][0];   // h2(t-2)
      acc1[0] = __builtin_amdgcn_mfma_f32_16x16x32_f16(A0[0][kc], B1, acc1[0], 0,0,0);
      acc1[1] = __builtin_amdgcn_mfma_f32_16x16x32_f16(A0[1][kc], B1, acc1[1], 0,0,0);
      acc2[0] = __builtin_amdgcn_mfma_f32_16x16x32_f16(A1[0][kc], B1, acc2[0], 0,0,0);
      acc2[1] = __builtin_amdgcn_mfma_f32_16x16x32_f16(A1[1][kc], B1, acc2[1], 0,0,0);
      acc2[0] = __builtin_amdgcn_mfma_f32_16x16x32_f16(A2[0][kc], B2, acc2[0], 0,0,0);
      acc2[1] = __builtin_amdgcn_mfma_f32_16x16x32_f16(A2[1][kc], B2, acc2[1], 0,0,0);
    }

    // h1(t) -> LDS B-frag layout (kc = w for a 32-row wave).
    // row k = w*32+mt*16+lq*4+r -> lane lm+16*(2mt+(lq>>1)), elem (lq&1)*4+r.
    if (t < T_STEPS){
      #pragma unroll
      for (int mt = 0; mt < 2; ++mt){
        union { _Float16 h[4]; unsigned long long u; } p;
        p.h[0]=(_Float16)tanh_fast(acc1[mt][0]); p.h[1]=(_Float16)tanh_fast(acc1[mt][1]);
        p.h[2]=(_Float16)tanh_fast(acc1[mt][2]); p.h[3]=(_Float16)tanh_fast(acc1[mt][3]);
        *(unsigned long long*)&h1f[cb][w][lm + 16*(mt*2 + (lq>>1))][(lq&1)*4] = p.u;
      }
    }
    // h2(t-1) -> LDS state + global out
    if (t > 0){
      #pragma unroll
      for (int mt = 0; mt < 2; ++mt){
        union { _Float16 h[4]; unsigned long long u; } q;
        q.h[0]=(_Float16)tanh_fast(acc2[mt][0]); q.h[1]=(_Float16)tanh_fast(acc2[mt][1]);
        q.h[2]=(_Float16)tanh_fast(acc2[mt][2]); q.h[3]=(_Float16)tanh_fast(acc2[mt][3]);
        *(unsigned long long*)&h2f[cb][w][lm + 16*(mt*2 + (lq>>1))][(lq&1)*4] = q.u;
        *(unsigned long long*)(hob + (size_t)(t-1)*64*HID + mt*16) = q.u;
      }
    }
    __syncthreads();
  }
}

// f16 -> fp32 final output, full-device, HBM-bound (~192 MiB moved).
__global__ __launch_bounds__(256) void cvt_out(
    const _Float16* __restrict__ hin, float* __restrict__ out)
{
  const long i = ((long)blockIdx.x*256 + threadIdx.x)*8;
  half8 v = *(const half8*)(hin + i);
  float4 a, b;
  a.x=(float)v[0]; a.y=(float)v[1]; a.z=(float)v[2]; a.w=(float)v[3];
  b.x=(float)v[4]; b.y=(float)v[5]; b.z=(float)v[6]; b.w=(float)v[7];
  *(float4*)(out + i)     = a;
  *(float4*)(out + i + 4) = b;
}

// ---------------------------------------------------------------------------
// Buffers: d_out low 64 MiB = xp0 (f16, dead before cvt_out); d_out + 64 MiB
// = wbuf (384 KB f16 weight frags, dead region until cvt_out overwrites at
// the very end). h2 f16 (64 MiB) -> d_ws; final fp32 -> d_out (128 MiB).
// ---------------------------------------------------------------------------
extern "C" void kernel_launch(void* const* d_in, const int* in_sizes, int n_in,
                              void* d_out, int out_size, void* d_ws, size_t ws_size,
                              hipStream_t stream)
{
  const float* x     = (const float*)d_in[0];
  const float* W_ih0 = (const float*)d_in[1];
  const float* W_hh0 = (const float*)d_in[2];
  const float* b_ih0 = (const float*)d_in[3];
  const float* b_hh0 = (const float*)d_in[4];
  const float* W_ih1 = (const float*)d_in[5];
  const float* W_hh1 = (const float*)d_in[6];
  const float* b_ih1 = (const float*)d_in[7];
  const float* b_hh1 = (const float*)d_in[8];

  _Float16* xp0  = (_Float16*)d_out;
  _Float16* wbuf = (_Float16*)((char*)d_out + (size_t)T_STEPS*64*HID*2);
  _Float16* h2   = (_Float16*)d_ws;

  wcvt<<<24, 64, 0, stream>>>(W_hh0, W_ih1, W_hh1, wbuf);
  gemm_xp0<<<T_STEPS, 512, 0, stream>>>(x, W_ih0, b_ih0, b_hh0, xp0);
  fused_rec<<<4, 512, 0, stream>>>(xp0, wbuf, b_ih1, b_hh1, h2);
  cvt_out<<<(T_STEPS*64*HID)/(256*8), 256, 0, stream>>>(h2, (float*)d_out);
}